// Round 2
// baseline (89.372 us; speedup 1.0000x reference)
//
#include <hip/hip_runtime.h>
#include <math.h>

// Problem constants (match reference)
#define BATCH 8192
#define NQ    512
#define NL    5

// Output layout (harness casts complex64 ref to float32 => REAL PARTS ONLY):
//   out[0 .. B*N*2)        : state reals, per (b,n): s0.re, s1.re
//   out[B*N*2 .. B*N*3)    : O real = |s0|^2 - |s1|^2
//
// Thread mapping: each thread owns one qubit index n (fixed), loops over a
// strided set of batch rows b (8 iterations). Per-n layer constants
// (fRx[j][n] and the Rz phase cos/sin) are computed once and reused.
__global__ __launch_bounds__(256) void qsim_kernel(
    const float* __restrict__ x,      // [BATCH][NQ]
    const float* __restrict__ fRx,    // [NL][NQ]
    const float* __restrict__ fRz,    // [NL][NQ]
    float* __restrict__ out)
{
    const int n  = (blockIdx.x & 1) * 256 + threadIdx.x;
    const int b0 = blockIdx.x >> 1;
    const int bstride = gridDim.x >> 1;

    // ---- per-qubit, per-layer constants (hoisted out of the b loop) ----
    float rx[NL];            // fRx[j][n]
    float pzr[NL], pzi[NL];  // Rz phase e^{-i c/2}: (cos(c/2), -sin(c/2))
#pragma unroll
    for (int j = 0; j < NL; ++j) {
        rx[j] = fRx[j * NQ + n];
        float c = fRz[j * NQ + n] * 0.5f;
        float s, cc;
        __sincosf(c, &s, &cc);
        pzr[j] = cc;
        pzi[j] = -s;
    }

    float* __restrict__ stateOut = out;                          // B*N float2 (s0.re, s1.re)
    float* __restrict__ oOut     = out + (size_t)BATCH * NQ * 2; // B*N floats

    for (int b = b0; b < BATCH; b += bstride) {
        const float xv = x[(size_t)b * NQ + n];

        // |0> state
        float s0r = 1.f, s0i = 0.f, s1r = 0.f, s1i = 0.f;

#pragma unroll
        for (int j = 0; j < NL; ++j) {
            // Rx(fRx[j]) then Rx(x) == Rx(x + fRx[j]) (same-axis rotations commute)
            const float half = (xv + rx[j]) * 0.5f;
            float sa, ca;
            __sincosf(half, &sa, &ca);
            // Rx: [ca, -i sa; -i sa, ca]
            float n0r =  ca * s0r + sa * s1i;
            float n0i =  ca * s0i - sa * s1r;
            float n1r =  sa * s0i + ca * s1r;
            float n1i = -sa * s0r + ca * s1i;
            // Rz: s0 *= (pzr + i pzi); s1 *= conj(pzr + i pzi)
            s0r = pzr[j] * n0r - pzi[j] * n0i;
            s0i = pzr[j] * n0i + pzi[j] * n0r;
            s1r = pzr[j] * n1r + pzi[j] * n1i;
            s1i = pzr[j] * n1i - pzi[j] * n1r;
        }

        const size_t idx = (size_t)b * NQ + n;
        // state real parts: one coalesced float2 per lane
        *reinterpret_cast<float2*>(stateOut + idx * 2) = make_float2(s0r, s1r);
        // O = |s0|^2 - |s1|^2 (real part; imag is exactly 0)
        oOut[idx] = (s0r * s0r + s0i * s0i) - (s1r * s1r + s1i * s1i);
    }
}

extern "C" void kernel_launch(void* const* d_in, const int* in_sizes, int n_in,
                              void* d_out, int out_size, void* d_ws, size_t ws_size,
                              hipStream_t stream) {
    const float* x   = (const float*)d_in[0];  // (B, N)
    const float* fRx = (const float*)d_in[1];  // (L, N)
    const float* fRz = (const float*)d_in[2];  // (L, N)
    float* out = (float*)d_out;

    dim3 grid(2048);
    dim3 block(256);
    qsim_kernel<<<grid, block, 0, stream>>>(x, fRx, fRz, out);
}